// Round 12
// baseline (186.610 us; speedup 1.0000x reference)
//
#include <hip/hip_runtime.h>
#include <math.h>

#define B 4
#define C 56
#define H 320
#define W 320
#define HC 313
#define WC 313
#define NIMG (H*W)          // 102400
#define NSP  (HC*WC)        // 97969
#define NPIX (B*NSP)        // 391876
#define NM   (B*NIMG)       // 409600
#define BN_EPS 1e-5f
#define YGRID 1536          // y1/y2 grid: 2 chunks/block, 24 waves/CU

// pool32 tile: 32x32 interior, 39x39 halo
#define PHR 39
#define NF4 390             // 39 rows x 10 float4 = whole tin incl. pad col

typedef __attribute__((ext_vector_type(8))) short short8;
typedef __attribute__((ext_vector_type(16))) float float16;
typedef __attribute__((ext_vector_type(4))) float f32x4;

__device__ __forceinline__ unsigned short f2bf(float v) {
  unsigned int u = __float_as_uint(v);
  return (unsigned short)((u + 0x7fffu + ((u >> 16) & 1u)) >> 16);
}

// ---------------------------------------------------------------------------
// pool32: one (32x32 tile, b, 8-ch group) per block. float4 halo staging
// (2 vector loads/thread), prefetch next channel, separable 8x8 boxsum,
// esum from LDS interior. p_t layout: [g][pix][8 ch] bf16 (R5-verified).
// ---------------------------------------------------------------------------
__global__ __launch_bounds__(256) void pool32_kernel(
    const float* __restrict__ x, float* __restrict__ Epart,
    unsigned short* __restrict__ p_t) {
  __shared__ float tin[PHR][40];            // 6240 B
  __shared__ float hs[PHR][32];             // 4992 B
  __shared__ unsigned short Pt[8][1024];    // 16384 B
  const int tid = threadIdx.x;
  int bid = blockIdx.x;
  const int g = bid % 7; bid /= 7;
  const int b = bid & 3; bid >>= 2;
  const int ty = bid / 10, tx = bid - (bid / 10) * 10;
  const int i0 = ty * 32, j0 = tx * 32;
  const float* xg = x + ((size_t)b * C + g * 8) * NIMG;

  // per-thread float4 halo slots (constant across channels)
  int r4[2], q4[2]; bool act[2], vld[2]; size_t xoff[2];
  #pragma unroll
  for (int k = 0; k < 2; ++k) {
    int idx = tid + k * 256;
    r4[k] = idx / 10; q4[k] = idx - r4[k] * 10;
    act[k] = idx < NF4;
    vld[k] = act[k] && (i0 + r4[k] < H) && (j0 + q4[k] * 4 < W);
    xoff[k] = (size_t)(i0 + r4[k]) * W + j0 + q4[k] * 4;
  }
  f32x4 cur4[2], nxt4[2];
  #pragma unroll
  for (int k = 0; k < 2; ++k)
    cur4[k] = vld[k] ? *(const f32x4*)(xg + xoff[k]) : (f32x4){0.f, 0.f, 0.f, 0.f};

  float esum[4] = {0.f, 0.f, 0.f, 0.f};

  #pragma unroll
  for (int c = 0; c < 8; ++c) {
    #pragma unroll
    for (int k = 0; k < 2; ++k)
      if (act[k]) *(f32x4*)&tin[r4[k]][q4[k] * 4] = cur4[k];
    __syncthreads();   // tin ready (and prev vsum hs-reads done)
    if (c < 7) {
      const float* xp = xg + (size_t)(c + 1) * NIMG;
      #pragma unroll
      for (int k = 0; k < 2; ++k)
        nxt4[k] = vld[k] ? *(const f32x4*)(xp + xoff[k]) : (f32x4){0.f, 0.f, 0.f, 0.f};
    }
    // horizontal 8-sums: 39 x 32
    #pragma unroll
    for (int it = 0; it < 5; ++it) {
      int idx = tid + it * 256;
      if (idx < PHR * 32) {
        int r = idx >> 5, j = idx & 31;
        float s = 0.f;
        #pragma unroll
        for (int d = 0; d < 8; ++d) s += tin[r][j + d];
        hs[r][j] = s;
      }
    }
    // esum over interior 32x32 (same barrier window as hsum)
    #pragma unroll
    for (int k = 0; k < 4; ++k) {
      int idx = tid + k * 256;
      esum[k] += tin[idx >> 5][idx & 31];
    }
    __syncthreads();   // hs ready
    // vertical 8-sums -> Pt (bf16)
    #pragma unroll
    for (int it = 0; it < 4; ++it) {
      int idx = tid + it * 256;
      int i = idx >> 5, j = idx & 31;
      float s = 0.f;
      #pragma unroll
      for (int d = 0; d < 8; ++d) s += hs[i + d][j];
      Pt[c][idx] = f2bf(s * (1.f / 64.f));
    }
    #pragma unroll
    for (int k = 0; k < 2; ++k) cur4[k] = nxt4[k];
  }
  __syncthreads();   // Pt complete

  // Epart: plain stores, each interior pixel owned by exactly one block
  float* Eb = Epart + ((size_t)g * B + b) * NIMG;
  #pragma unroll
  for (int k = 0; k < 4; ++k) {
    int idx = tid + k * 256;
    Eb[(i0 + (idx >> 5)) * W + j0 + (idx & 31)] = esum[k];
  }

  // p_t dump: 16B per valid pixel, coalesced (R5-verified)
  unsigned short* pg = p_t + (size_t)g * NPIX * 8;
  #pragma unroll
  for (int k = 0; k < 4; ++k) {
    int idx = tid + k * 256;
    int i = idx >> 5, j = idx & 31;
    int gi = i0 + i, gj = j0 + j;
    if (gi < HC && gj < WC) {
      unsigned short t8[8];
      #pragma unroll
      for (int c2 = 0; c2 < 8; ++c2) t8[c2] = Pt[c2][idx];
      *(short8*)(pg + ((size_t)b * NSP + gi * WC + gj) * 8) = *(short8*)t8;
    }
  }
}

// ---------------------------------------------------------------------------
// se_pool (R5-verified, verbatim)
// ---------------------------------------------------------------------------
__global__ __launch_bounds__(256) void se_pool_kernel(
    const float* __restrict__ Epart, float* __restrict__ E, float* __restrict__ S) {
  __shared__ float tin[39][40];
  __shared__ float hs[39][33];
  const int b = blockIdx.z;
  const int i0 = blockIdx.y * 32, j0 = blockIdx.x * 32;
  const int tid = threadIdx.x;
  for (int idx = tid; idx < 39 * 39; idx += 256) {
    int r = idx / 39, cc = idx - r * 39;
    int gi = i0 + r, gj = j0 + cc;
    float v = 0.f;
    if (gi < H && gj < W) {
      float s = 0.f;
      #pragma unroll
      for (int g = 0; g < 7; ++g)
        s += Epart[((size_t)g * B + b) * NIMG + gi * W + gj];
      v = expf(s * (1.f / C));
      if (r < 32 && cc < 32) E[(size_t)b * NIMG + gi * W + gj] = v;
    }
    tin[r][cc] = v;
  }
  __syncthreads();
  for (int idx = tid; idx < 39 * 32; idx += 256) {
    int r = idx >> 5, j = idx & 31;
    float s = 0.f;
    #pragma unroll
    for (int d = 0; d < 8; ++d) s += tin[r][j + d];
    hs[r][j] = s;
  }
  __syncthreads();
  for (int idx = tid; idx < 32 * 32; idx += 256) {
    int i = idx >> 5, j = idx & 31;
    int gi = i0 + i, gj = j0 + j;
    if (gi < HC && gj < WC) {
      float s = 0.f;
      #pragma unroll
      for (int d = 0; d < 8; ++d) s += hs[i + d][j];
      S[(size_t)b * NSP + gi * WC + gj] = s;
    }
  }
}

// ---------------------------------------------------------------------------
// y1_stats (R11-verified body, grid 1536 = 2 chunks/block): MFMA y1 sums,
// plain-store 112-float partials per block. Wl overlaid on red (dead after
// fragment load; barrier-separated).
// ---------------------------------------------------------------------------
__global__ __launch_bounds__(256) void y1_stats_kernel(
    const unsigned short* __restrict__ p_t, const float* __restrict__ w1,
    float* __restrict__ ypart) {
  __shared__ float red[4][32][64];   // 32 KB; first 8 KB doubles as Wl
  unsigned short* Wl = (unsigned short*)&red[0][0][0];
  const int tid = threadIdx.x, wave = tid >> 6, lane = tid & 63;
  for (int idx = tid; idx < 4096; idx += 256) {
    int o = idx >> 6, k = idx & 63;
    float v = (o < C && k < C) ? w1[o * C + k] : 0.f;
    *(unsigned short*)((char*)Wl + (o * 128 + ((2 * k) ^ ((o & 7) << 4)))) = f2bf(v);
  }
  __syncthreads();
  short8 afr[2][4];
  #pragma unroll
  for (int q = 0; q < 2; ++q)
    #pragma unroll
    for (int ks = 0; ks < 4; ++ks) {
      int row = q * 32 + (lane & 31), kb = ks * 16 + 8 * (lane >> 5);
      afr[q][ks] = *(const short8*)((const char*)Wl + row * 128 + ((2 * kb) ^ ((row & 7) << 4)));
    }
  float s1[2][16], s2[2][16];
  #pragma unroll
  for (int q = 0; q < 2; ++q)
    #pragma unroll
    for (int r = 0; r < 16; ++r) { s1[q][r] = 0.f; s2[q][r] = 0.f; }

  const int h = lane >> 5;
  const int nchunk = (NPIX + 127) / 128;   // 3062
  for (int ch = blockIdx.x; ch < nchunk; ch += YGRID) {
    int col = ch * 128 + wave * 32 + (lane & 31);
    bool cv = col < NPIX;
    size_t pofs = (size_t)(cv ? col : 0) * 8;
    short8 bfr[4];
    #pragma unroll
    for (int ks = 0; ks < 4; ++ks) {
      int g = ks * 2 + h;
      short8 bv = (short8){0, 0, 0, 0, 0, 0, 0, 0};
      if (g < 7 && cv) bv = *(const short8*)(p_t + (size_t)g * NPIX * 8 + pofs);
      bfr[ks] = bv;
    }
    float16 a0 = {}, a1 = {};
    #pragma unroll
    for (int ks = 0; ks < 4; ++ks) {
      a0 = __builtin_amdgcn_mfma_f32_32x32x16_bf16(afr[0][ks], bfr[ks], a0, 0, 0, 0);
      a1 = __builtin_amdgcn_mfma_f32_32x32x16_bf16(afr[1][ks], bfr[ks], a1, 0, 0, 0);
    }
    #pragma unroll
    for (int r = 0; r < 16; ++r) {
      s1[0][r] += a0[r]; s2[0][r] = fmaf(a0[r], a0[r], s2[0][r]);
      s1[1][r] += a1[r]; s2[1][r] = fmaf(a1[r], a1[r], s2[1][r]);
    }
  }
  // flush: pass 0 = sums, pass 1 = sumsq (R11-verified mapping)
  for (int pass = 0; pass < 2; ++pass) {
    __syncthreads();
    #pragma unroll
    for (int q = 0; q < 2; ++q)
      #pragma unroll
      for (int r = 0; r < 16; ++r)
        red[wave][q * 16 + r][lane] = pass ? s2[q][r] : s1[q][r];
    __syncthreads();
    if (tid < C) {
      int row = tid, q = row >> 5, rr = row & 31;
      int hh = (rr >> 2) & 1, reg = (rr & 3) | ((rr >> 3) << 2);
      float s = 0.f;
      #pragma unroll
      for (int w = 0; w < 4; ++w)
        #pragma unroll
        for (int cl = 0; cl < 32; ++cl)
          s += red[w][q * 16 + reg][32 * hh + cl];
      ypart[blockIdx.x * 112 + pass * 56 + row] = s;
    }
  }
}

// ---------------------------------------------------------------------------
// ypart_bn1: reduce YGRID partials (112x8 threads) + BN1 coefficients.
// ---------------------------------------------------------------------------
__global__ void ypart_bn1_kernel(const float* __restrict__ ypart,
                                 const float* __restrict__ g1, const float* __restrict__ be1,
                                 float* __restrict__ ac) {
  __shared__ float part[8][112];
  int t = threadIdx.x;       // 0..111
  int ty = threadIdx.y;      // 0..7
  float s = 0.f;
  for (int b = ty; b < YGRID; b += 8) s += ypart[b * 112 + t];
  part[ty][t] = s;
  __syncthreads();
  if (ty == 0) {
    float tot = 0.f;
    #pragma unroll
    for (int k = 0; k < 8; ++k) tot += part[k][t];
    part[0][t] = tot;
  }
  __syncthreads();
  if (ty == 0 && t < C) {
    float m = part[0][t] * (1.f / NPIX);
    float var = part[0][56 + t] * (1.f / NPIX) - m * m;
    float a = g1[t] * rsqrtf(var + BN_EPS);
    ac[t] = a;
    ac[C + t] = fmaf(-a, m, be1[t]);
  }
}

// ---------------------------------------------------------------------------
// y2 (R11-verified body, grid 1536): d2 = w2 . relu(af*(W1 p) + cf); BN2
// stats binned (2 atomics/block).
// ---------------------------------------------------------------------------
__global__ __launch_bounds__(256) void y2_kernel(
    const unsigned short* __restrict__ p_t, const float* __restrict__ w1,
    const float* __restrict__ ac, const float* __restrict__ w2,
    float* __restrict__ y2, float* __restrict__ stats2) {
  __shared__ unsigned short Wl[64 * 64];
  __shared__ float af[64], cf[64], wf[64];
  const int tid = threadIdx.x, wave = tid >> 6, lane = tid & 63;
  for (int idx = tid; idx < 4096; idx += 256) {
    int o = idx >> 6, k = idx & 63;
    float v = (o < C && k < C) ? w1[o * C + k] : 0.f;
    *(unsigned short*)((char*)Wl + (o * 128 + ((2 * k) ^ ((o & 7) << 4)))) = f2bf(v);
  }
  if (tid < 64) {
    bool ok = tid < C;
    af[tid] = ok ? ac[tid] : 0.f;
    cf[tid] = ok ? ac[C + tid] : 0.f;
    wf[tid] = ok ? w2[tid] : 0.f;
  }
  __syncthreads();
  short8 afr[2][4];
  #pragma unroll
  for (int q = 0; q < 2; ++q)
    #pragma unroll
    for (int ks = 0; ks < 4; ++ks) {
      int row = q * 32 + (lane & 31), kb = ks * 16 + 8 * (lane >> 5);
      afr[q][ks] = *(const short8*)((const char*)Wl + row * 128 + ((2 * kb) ^ ((row & 7) << 4)));
    }
  const int h = lane >> 5;
  float ss1 = 0.f, ss2 = 0.f;
  const int nchunk = (NPIX + 127) / 128;
  for (int ch = blockIdx.x; ch < nchunk; ch += YGRID) {
    int col = ch * 128 + wave * 32 + (lane & 31);
    bool cv = col < NPIX;
    size_t pofs = (size_t)(cv ? col : 0) * 8;
    short8 bfr[4];
    #pragma unroll
    for (int ks = 0; ks < 4; ++ks) {
      int g = ks * 2 + h;
      short8 bv = (short8){0, 0, 0, 0, 0, 0, 0, 0};
      if (g < 7 && cv) bv = *(const short8*)(p_t + (size_t)g * NPIX * 8 + pofs);
      bfr[ks] = bv;
    }
    float16 a0 = {}, a1 = {};
    #pragma unroll
    for (int ks = 0; ks < 4; ++ks) {
      a0 = __builtin_amdgcn_mfma_f32_32x32x16_bf16(afr[0][ks], bfr[ks], a0, 0, 0, 0);
      a1 = __builtin_amdgcn_mfma_f32_32x32x16_bf16(afr[1][ks], bfr[ks], a1, 0, 0, 0);
    }
    float ysum = 0.f;
    #pragma unroll
    for (int r = 0; r < 16; ++r) {
      int o0 = (r & 3) + 8 * (r >> 2) + 4 * h;
      ysum = fmaf(wf[o0], fmaxf(fmaf(af[o0], a0[r], cf[o0]), 0.f), ysum);
      int o1 = o0 + 32;
      ysum = fmaf(wf[o1], fmaxf(fmaf(af[o1], a1[r], cf[o1]), 0.f), ysum);
    }
    ysum += __shfl_xor(ysum, 32);
    bool wr = cv && lane < 32;
    if (wr) {
      y2[col] = ysum;
      ss1 += ysum;
      ss2 = fmaf(ysum, ysum, ss2);
    }
  }
  #pragma unroll
  for (int off = 1; off < 64; off <<= 1) {
    ss1 += __shfl_xor(ss1, off);
    ss2 += __shfl_xor(ss2, off);
  }
  if (lane == 0) {
    atomicAdd(&stats2[(blockIdx.x & 63) * 2 + 0], ss1);
    atomicAdd(&stats2[(blockIdx.x & 63) * 2 + 1], ss2);
  }
}

__global__ void bn2_final_kernel(const float* __restrict__ stats2,
                                 const float* __restrict__ g2, const float* __restrict__ be2,
                                 float* __restrict__ a2c2) {
  int t = threadIdx.x;   // 64 threads
  float s1 = stats2[t * 2], s2 = stats2[t * 2 + 1];
  #pragma unroll
  for (int off = 32; off > 0; off >>= 1) {
    s1 += __shfl_down(s1, off);
    s2 += __shfl_down(s2, off);
  }
  if (t == 0) {
    float mean = s1 * (1.f / NPIX);
    float var  = s2 * (1.f / NPIX) - mean * mean;
    float a = g2[0] * rsqrtf(var + BN_EPS);
    a2c2[0] = a;
    a2c2[1] = fmaf(-a, mean, be2[0]);
  }
}

// ---------------------------------------------------------------------------
// r_pool (R5-verified, verbatim)
// ---------------------------------------------------------------------------
__global__ __launch_bounds__(256) void r_pool_kernel(
    const float* __restrict__ y2, const float* __restrict__ S,
    const float* __restrict__ a2c2, const float* __restrict__ E,
    float* __restrict__ cout, float* __restrict__ R) {
  __shared__ float tin[39][40];
  __shared__ float hs[39][33];
  const int b = blockIdx.z;
  const int i0 = blockIdx.y * 32, j0 = blockIdx.x * 32;
  const int tid = threadIdx.x;
  const float a2 = a2c2[0], c2 = a2c2[1];
  const float* y2b = y2 + (size_t)b * NSP;
  const float* Sb  = S + (size_t)b * NSP;
  float* cb = cout + (size_t)b * NSP;
  for (int idx = tid; idx < 39 * 39; idx += 256) {
    int r = idx / 39, cc = idx - r * 39;
    int gi = i0 + r - 7, gj = j0 + cc - 7;
    float t = 0.f;
    if (gi >= 0 && gi < HC && gj >= 0 && gj < WC) {
      float v = fmaxf(fmaf(a2, y2b[gi * WC + gj], c2), 0.f);
      t = v / Sb[gi * WC + gj];
      if (r >= 7 && cc >= 7) cb[gi * WC + gj] = v;
    }
    tin[r][cc] = t;
  }
  __syncthreads();
  for (int idx = tid; idx < 39 * 32; idx += 256) {
    int r = idx >> 5, j = idx & 31;
    float s = 0.f;
    #pragma unroll
    for (int d = 0; d < 8; ++d) s += tin[r][j + d];
    hs[r][j] = s;
  }
  __syncthreads();
  for (int idx = tid; idx < 32 * 32; idx += 256) {
    int i = idx >> 5, j = idx & 31;
    size_t gofs = (size_t)b * NIMG + (i0 + i) * W + (j0 + j);
    float s = 0.f;
    #pragma unroll
    for (int d = 0; d < 8; ++d) s += hs[i + d][j];
    R[gofs] = E[gofs] * s;
  }
}

extern "C" void kernel_launch(void* const* d_in, const int* in_sizes, int n_in,
                              void* d_out, int out_size, void* d_ws, size_t ws_size,
                              hipStream_t stream) {
  const float* x   = (const float*)d_in[0];
  const float* w1  = (const float*)d_in[1];
  const float* w2  = (const float*)d_in[3];
  const float* g1  = (const float*)d_in[5];
  const float* be1 = (const float*)d_in[6];
  const float* g2  = (const float*)d_in[7];
  const float* be2 = (const float*)d_in[8];

  float* out_c = (float*)d_out;          // C_out: NPIX floats
  float* out_r = out_c + NPIX;           // R: NM floats

  // workspace: p_t 43.9 MB + Epart 11.5 + E 1.6 + S/y2 0.8 + ypart 0.7 ≈ 59 MB
  unsigned short* p_t = (unsigned short*)d_ws;          // [7][NPIX][8] bf16
  float* fbase = (float*)(p_t + (size_t)7 * NPIX * 8);
  size_t off = 0;
  float* Epart  = fbase + off; off += (size_t)7 * NM;
  float* E      = fbase + off; off += NM;
  float* Sarr   = fbase + off; off += NPIX;
  float* y2     = fbase + off; off += NPIX;
  float* ypart  = fbase + off; off += (size_t)YGRID * 112;
  float* stats2 = fbase + off; off += 128;
  float* ac     = fbase + off; off += 112;
  float* a2c2   = fbase + off; off += 2;

  hipMemsetAsync(stats2, 0, 128 * sizeof(float), stream);

  pool32_kernel<<<100 * B * 7, 256, 0, stream>>>(x, Epart, p_t);

  dim3 sg(10, 10, B);
  se_pool_kernel<<<sg, 256, 0, stream>>>(Epart, E, Sarr);

  y1_stats_kernel<<<YGRID, 256, 0, stream>>>(p_t, w1, ypart);
  ypart_bn1_kernel<<<1, dim3(112, 8), 0, stream>>>(ypart, g1, be1, ac);
  y2_kernel<<<YGRID, 256, 0, stream>>>(p_t, w1, ac, w2, y2, stats2);
  bn2_final_kernel<<<1, 64, 0, stream>>>(stats2, g2, be2, a2c2);

  dim3 rg(10, 10, B);
  r_pool_kernel<<<rg, 256, 0, stream>>>(y2, Sarr, a2c2, E, out_c, out_r);
}

// Round 13
// 118.247 us; speedup vs baseline: 1.5781x; 1.5781x over previous
//
#include <hip/hip_runtime.h>
#include <math.h>

#define B 4
#define C 56
#define H 320
#define W 320
#define HC 313
#define WC 313
#define NIMG (H*W)          // 102400
#define NSP  (HC*WC)        // 97969
#define NPIX (B*NSP)        // 391876
#define NM   (B*NIMG)       // 409600
#define BN_EPS 1e-5f
#define NGRID 512           // y1/y2 grid (R11-proven; 1536/3062 regress)

// pool32 tile: 32x32 interior, 39x39 halo
#define PHR 39
#define NF4 390             // 39 rows x 10 float4 = whole tin incl. pad col

typedef __attribute__((ext_vector_type(8))) short short8;
typedef __attribute__((ext_vector_type(16))) float float16;
typedef __attribute__((ext_vector_type(4))) float f32x4;

__device__ __forceinline__ unsigned short f2bf(float v) {
  unsigned int u = __float_as_uint(v);
  return (unsigned short)((u + 0x7fffu + ((u >> 16) & 1u)) >> 16);
}

// ---------------------------------------------------------------------------
// pool32 (R12-verified float4 staging): one (32x32 tile, b, 8-ch group) per
// block. esum now accumulated in f32x4 registers (interior float4 slots) and
// stored vectorized — no LDS re-read. p_t layout: [g][pix][8 ch] bf16.
// ---------------------------------------------------------------------------
__global__ __launch_bounds__(256) void pool32_kernel(
    const float* __restrict__ x, float* __restrict__ Epart,
    unsigned short* __restrict__ p_t) {
  __shared__ float tin[PHR][40];            // 6240 B
  __shared__ float hs[PHR][32];             // 4992 B
  __shared__ unsigned short Pt[8][1024];    // 16384 B
  const int tid = threadIdx.x;
  int bid = blockIdx.x;
  const int g = bid % 7; bid /= 7;
  const int b = bid & 3; bid >>= 2;
  const int ty = bid / 10, tx = bid - (bid / 10) * 10;
  const int i0 = ty * 32, j0 = tx * 32;
  const float* xg = x + ((size_t)b * C + g * 8) * NIMG;

  // per-thread float4 halo slots (constant across channels)
  int r4[2], q4[2]; bool act[2], vld[2], inter[2]; size_t xoff[2];
  #pragma unroll
  for (int k = 0; k < 2; ++k) {
    int idx = tid + k * 256;
    r4[k] = idx / 10; q4[k] = idx - r4[k] * 10;
    act[k] = idx < NF4;
    vld[k] = act[k] && (i0 + r4[k] < H) && (j0 + q4[k] * 4 < W);
    inter[k] = act[k] && r4[k] < 32 && q4[k] < 8;   // fully-interior float4
    xoff[k] = (size_t)(i0 + r4[k]) * W + j0 + q4[k] * 4;
  }
  f32x4 cur4[2], nxt4[2];
  #pragma unroll
  for (int k = 0; k < 2; ++k)
    cur4[k] = vld[k] ? *(const f32x4*)(xg + xoff[k]) : (f32x4){0.f, 0.f, 0.f, 0.f};

  f32x4 esum4[2] = {{0.f, 0.f, 0.f, 0.f}, {0.f, 0.f, 0.f, 0.f}};

  #pragma unroll
  for (int c = 0; c < 8; ++c) {
    #pragma unroll
    for (int k = 0; k < 2; ++k) {
      if (act[k]) *(f32x4*)&tin[r4[k]][q4[k] * 4] = cur4[k];
      if (inter[k]) esum4[k] += cur4[k];
    }
    __syncthreads();   // tin ready (and prev vsum hs-reads done)
    if (c < 7) {
      const float* xp = xg + (size_t)(c + 1) * NIMG;
      #pragma unroll
      for (int k = 0; k < 2; ++k)
        nxt4[k] = vld[k] ? *(const f32x4*)(xp + xoff[k]) : (f32x4){0.f, 0.f, 0.f, 0.f};
    }
    // horizontal 8-sums: 39 x 32
    #pragma unroll
    for (int it = 0; it < 5; ++it) {
      int idx = tid + it * 256;
      if (idx < PHR * 32) {
        int r = idx >> 5, j = idx & 31;
        float s = 0.f;
        #pragma unroll
        for (int d = 0; d < 8; ++d) s += tin[r][j + d];
        hs[r][j] = s;
      }
    }
    __syncthreads();   // hs ready
    // vertical 8-sums -> Pt (bf16)
    #pragma unroll
    for (int it = 0; it < 4; ++it) {
      int idx = tid + it * 256;
      int i = idx >> 5, j = idx & 31;
      float s = 0.f;
      #pragma unroll
      for (int d = 0; d < 8; ++d) s += hs[i + d][j];
      Pt[c][idx] = f2bf(s * (1.f / 64.f));
    }
    #pragma unroll
    for (int k = 0; k < 2; ++k) cur4[k] = nxt4[k];
  }
  __syncthreads();   // Pt complete

  // Epart: vectorized plain stores (each interior float4 owned by one block)
  float* Eb = Epart + ((size_t)g * B + b) * NIMG;
  #pragma unroll
  for (int k = 0; k < 2; ++k)
    if (inter[k]) *(f32x4*)&Eb[(i0 + r4[k]) * W + j0 + q4[k] * 4] = esum4[k];

  // p_t dump: 16B per valid pixel, coalesced (R5-verified)
  unsigned short* pg = p_t + (size_t)g * NPIX * 8;
  #pragma unroll
  for (int k = 0; k < 4; ++k) {
    int idx = tid + k * 256;
    int i = idx >> 5, j = idx & 31;
    int gi = i0 + i, gj = j0 + j;
    if (gi < HC && gj < WC) {
      unsigned short t8[8];
      #pragma unroll
      for (int c2 = 0; c2 < 8; ++c2) t8[c2] = Pt[c2][idx];
      *(short8*)(pg + ((size_t)b * NSP + gi * WC + gj) * 8) = *(short8*)t8;
    }
  }
}

// ---------------------------------------------------------------------------
// se_pool (R5-verified, verbatim)
// ---------------------------------------------------------------------------
__global__ __launch_bounds__(256) void se_pool_kernel(
    const float* __restrict__ Epart, float* __restrict__ E, float* __restrict__ S) {
  __shared__ float tin[39][40];
  __shared__ float hs[39][33];
  const int b = blockIdx.z;
  const int i0 = blockIdx.y * 32, j0 = blockIdx.x * 32;
  const int tid = threadIdx.x;
  for (int idx = tid; idx < 39 * 39; idx += 256) {
    int r = idx / 39, cc = idx - r * 39;
    int gi = i0 + r, gj = j0 + cc;
    float v = 0.f;
    if (gi < H && gj < W) {
      float s = 0.f;
      #pragma unroll
      for (int g = 0; g < 7; ++g)
        s += Epart[((size_t)g * B + b) * NIMG + gi * W + gj];
      v = expf(s * (1.f / C));
      if (r < 32 && cc < 32) E[(size_t)b * NIMG + gi * W + gj] = v;
    }
    tin[r][cc] = v;
  }
  __syncthreads();
  for (int idx = tid; idx < 39 * 32; idx += 256) {
    int r = idx >> 5, j = idx & 31;
    float s = 0.f;
    #pragma unroll
    for (int d = 0; d < 8; ++d) s += tin[r][j + d];
    hs[r][j] = s;
  }
  __syncthreads();
  for (int idx = tid; idx < 32 * 32; idx += 256) {
    int i = idx >> 5, j = idx & 31;
    int gi = i0 + i, gj = j0 + j;
    if (gi < HC && gj < WC) {
      float s = 0.f;
      #pragma unroll
      for (int d = 0; d < 8; ++d) s += hs[i + d][j];
      S[(size_t)b * NSP + gi * WC + gj] = s;
    }
  }
}

// ---------------------------------------------------------------------------
// y1_stats (R11-verified, verbatim: 512 blocks, 6 chunks, register s1/s2,
// plain-store 112-float partials per block).
// ---------------------------------------------------------------------------
__global__ __launch_bounds__(256) void y1_stats_kernel(
    const unsigned short* __restrict__ p_t, const float* __restrict__ w1,
    float* __restrict__ ypart) {
  __shared__ unsigned short Wl[64 * 64];
  __shared__ float red[4][32][64];   // 32 KB, used only in flush
  const int tid = threadIdx.x, wave = tid >> 6, lane = tid & 63;
  for (int idx = tid; idx < 4096; idx += 256) {
    int o = idx >> 6, k = idx & 63;
    float v = (o < C && k < C) ? w1[o * C + k] : 0.f;
    *(unsigned short*)((char*)Wl + (o * 128 + ((2 * k) ^ ((o & 7) << 4)))) = f2bf(v);
  }
  __syncthreads();
  short8 afr[2][4];
  #pragma unroll
  for (int q = 0; q < 2; ++q)
    #pragma unroll
    for (int ks = 0; ks < 4; ++ks) {
      int row = q * 32 + (lane & 31), kb = ks * 16 + 8 * (lane >> 5);
      afr[q][ks] = *(const short8*)((const char*)Wl + row * 128 + ((2 * kb) ^ ((row & 7) << 4)));
    }
  float s1[2][16], s2[2][16];
  #pragma unroll
  for (int q = 0; q < 2; ++q)
    #pragma unroll
    for (int r = 0; r < 16; ++r) { s1[q][r] = 0.f; s2[q][r] = 0.f; }

  const int h = lane >> 5;
  const int nchunk = (NPIX + 127) / 128;   // 3062
  for (int ch = blockIdx.x; ch < nchunk; ch += NGRID) {
    int col = ch * 128 + wave * 32 + (lane & 31);
    bool cv = col < NPIX;
    size_t pofs = (size_t)(cv ? col : 0) * 8;
    short8 bfr[4];
    #pragma unroll
    for (int ks = 0; ks < 4; ++ks) {
      int g = ks * 2 + h;
      short8 bv = (short8){0, 0, 0, 0, 0, 0, 0, 0};
      if (g < 7 && cv) bv = *(const short8*)(p_t + (size_t)g * NPIX * 8 + pofs);
      bfr[ks] = bv;
    }
    float16 a0 = {}, a1 = {};
    #pragma unroll
    for (int ks = 0; ks < 4; ++ks) {
      a0 = __builtin_amdgcn_mfma_f32_32x32x16_bf16(afr[0][ks], bfr[ks], a0, 0, 0, 0);
      a1 = __builtin_amdgcn_mfma_f32_32x32x16_bf16(afr[1][ks], bfr[ks], a1, 0, 0, 0);
    }
    #pragma unroll
    for (int r = 0; r < 16; ++r) {
      s1[0][r] += a0[r]; s2[0][r] = fmaf(a0[r], a0[r], s2[0][r]);
      s1[1][r] += a1[r]; s2[1][r] = fmaf(a1[r], a1[r], s2[1][r]);
    }
  }
  // flush: pass 0 = sums, pass 1 = sumsq (R11-verified mapping)
  for (int pass = 0; pass < 2; ++pass) {
    __syncthreads();
    #pragma unroll
    for (int q = 0; q < 2; ++q)
      #pragma unroll
      for (int r = 0; r < 16; ++r)
        red[wave][q * 16 + r][lane] = pass ? s2[q][r] : s1[q][r];
    __syncthreads();
    if (tid < C) {
      int row = tid, q = row >> 5, rr = row & 31;
      int hh = (rr >> 2) & 1, reg = (rr & 3) | ((rr >> 3) << 2);
      float s = 0.f;
      #pragma unroll
      for (int w = 0; w < 4; ++w)
        #pragma unroll
        for (int cl = 0; cl < 32; ++cl)
          s += red[w][q * 16 + reg][32 * hh + cl];
      ypart[blockIdx.x * 112 + pass * 56 + row] = s;
    }
  }
}

// ---------------------------------------------------------------------------
// ypart_bn1 (R11-verified, verbatim): reduce 512 partials + BN1 coefficients.
// ---------------------------------------------------------------------------
__global__ void ypart_bn1_kernel(const float* __restrict__ ypart,
                                 const float* __restrict__ g1, const float* __restrict__ be1,
                                 float* __restrict__ ac) {
  __shared__ float sums[112];
  int t = threadIdx.x;   // 128 threads
  if (t < 112) {
    float s0 = 0.f, s1 = 0.f, s2 = 0.f, s3 = 0.f;
    #pragma unroll 4
    for (int b = 0; b < NGRID; b += 4) {
      s0 += ypart[(b + 0) * 112 + t];
      s1 += ypart[(b + 1) * 112 + t];
      s2 += ypart[(b + 2) * 112 + t];
      s3 += ypart[(b + 3) * 112 + t];
    }
    sums[t] = (s0 + s1) + (s2 + s3);
  }
  __syncthreads();
  if (t < C) {
    float m = sums[t] * (1.f / NPIX);
    float var = sums[56 + t] * (1.f / NPIX) - m * m;
    float a = g1[t] * rsqrtf(var + BN_EPS);
    ac[t] = a;
    ac[C + t] = fmaf(-a, m, be1[t]);
  }
}

// ---------------------------------------------------------------------------
// y2 (R11-verified, verbatim: 512 blocks): d2 = w2 . relu(af*(W1 p) + cf);
// BN2 stats binned (2 atomics/block — negligible).
// ---------------------------------------------------------------------------
__global__ __launch_bounds__(256) void y2_kernel(
    const unsigned short* __restrict__ p_t, const float* __restrict__ w1,
    const float* __restrict__ ac, const float* __restrict__ w2,
    float* __restrict__ y2, float* __restrict__ stats2) {
  __shared__ unsigned short Wl[64 * 64];
  __shared__ float af[64], cf[64], wf[64];
  const int tid = threadIdx.x, wave = tid >> 6, lane = tid & 63;
  for (int idx = tid; idx < 4096; idx += 256) {
    int o = idx >> 6, k = idx & 63;
    float v = (o < C && k < C) ? w1[o * C + k] : 0.f;
    *(unsigned short*)((char*)Wl + (o * 128 + ((2 * k) ^ ((o & 7) << 4)))) = f2bf(v);
  }
  if (tid < 64) {
    bool ok = tid < C;
    af[tid] = ok ? ac[tid] : 0.f;
    cf[tid] = ok ? ac[C + tid] : 0.f;
    wf[tid] = ok ? w2[tid] : 0.f;
  }
  __syncthreads();
  short8 afr[2][4];
  #pragma unroll
  for (int q = 0; q < 2; ++q)
    #pragma unroll
    for (int ks = 0; ks < 4; ++ks) {
      int row = q * 32 + (lane & 31), kb = ks * 16 + 8 * (lane >> 5);
      afr[q][ks] = *(const short8*)((const char*)Wl + row * 128 + ((2 * kb) ^ ((row & 7) << 4)));
    }
  const int h = lane >> 5;
  float ss1 = 0.f, ss2 = 0.f;
  const int nchunk = (NPIX + 127) / 128;
  for (int ch = blockIdx.x; ch < nchunk; ch += NGRID) {
    int col = ch * 128 + wave * 32 + (lane & 31);
    bool cv = col < NPIX;
    size_t pofs = (size_t)(cv ? col : 0) * 8;
    short8 bfr[4];
    #pragma unroll
    for (int ks = 0; ks < 4; ++ks) {
      int g = ks * 2 + h;
      short8 bv = (short8){0, 0, 0, 0, 0, 0, 0, 0};
      if (g < 7 && cv) bv = *(const short8*)(p_t + (size_t)g * NPIX * 8 + pofs);
      bfr[ks] = bv;
    }
    float16 a0 = {}, a1 = {};
    #pragma unroll
    for (int ks = 0; ks < 4; ++ks) {
      a0 = __builtin_amdgcn_mfma_f32_32x32x16_bf16(afr[0][ks], bfr[ks], a0, 0, 0, 0);
      a1 = __builtin_amdgcn_mfma_f32_32x32x16_bf16(afr[1][ks], bfr[ks], a1, 0, 0, 0);
    }
    float ysum = 0.f;
    #pragma unroll
    for (int r = 0; r < 16; ++r) {
      int o0 = (r & 3) + 8 * (r >> 2) + 4 * h;
      ysum = fmaf(wf[o0], fmaxf(fmaf(af[o0], a0[r], cf[o0]), 0.f), ysum);
      int o1 = o0 + 32;
      ysum = fmaf(wf[o1], fmaxf(fmaf(af[o1], a1[r], cf[o1]), 0.f), ysum);
    }
    ysum += __shfl_xor(ysum, 32);
    bool wr = cv && lane < 32;
    if (wr) {
      y2[col] = ysum;
      ss1 += ysum;
      ss2 = fmaf(ysum, ysum, ss2);
    }
  }
  #pragma unroll
  for (int off = 1; off < 64; off <<= 1) {
    ss1 += __shfl_xor(ss1, off);
    ss2 += __shfl_xor(ss2, off);
  }
  if (lane == 0) {
    atomicAdd(&stats2[(blockIdx.x & 63) * 2 + 0], ss1);
    atomicAdd(&stats2[(blockIdx.x & 63) * 2 + 1], ss2);
  }
}

__global__ void bn2_final_kernel(const float* __restrict__ stats2,
                                 const float* __restrict__ g2, const float* __restrict__ be2,
                                 float* __restrict__ a2c2) {
  int t = threadIdx.x;   // 64 threads
  float s1 = stats2[t * 2], s2 = stats2[t * 2 + 1];
  #pragma unroll
  for (int off = 32; off > 0; off >>= 1) {
    s1 += __shfl_down(s1, off);
    s2 += __shfl_down(s2, off);
  }
  if (t == 0) {
    float mean = s1 * (1.f / NPIX);
    float var  = s2 * (1.f / NPIX) - mean * mean;
    float a = g2[0] * rsqrtf(var + BN_EPS);
    a2c2[0] = a;
    a2c2[1] = fmaf(-a, mean, be2[0]);
  }
}

// ---------------------------------------------------------------------------
// r_pool (R5-verified, verbatim)
// ---------------------------------------------------------------------------
__global__ __launch_bounds__(256) void r_pool_kernel(
    const float* __restrict__ y2, const float* __restrict__ S,
    const float* __restrict__ a2c2, const float* __restrict__ E,
    float* __restrict__ cout, float* __restrict__ R) {
  __shared__ float tin[39][40];
  __shared__ float hs[39][33];
  const int b = blockIdx.z;
  const int i0 = blockIdx.y * 32, j0 = blockIdx.x * 32;
  const int tid = threadIdx.x;
  const float a2 = a2c2[0], c2 = a2c2[1];
  const float* y2b = y2 + (size_t)b * NSP;
  const float* Sb  = S + (size_t)b * NSP;
  float* cb = cout + (size_t)b * NSP;
  for (int idx = tid; idx < 39 * 39; idx += 256) {
    int r = idx / 39, cc = idx - r * 39;
    int gi = i0 + r - 7, gj = j0 + cc - 7;
    float t = 0.f;
    if (gi >= 0 && gi < HC && gj >= 0 && gj < WC) {
      float v = fmaxf(fmaf(a2, y2b[gi * WC + gj], c2), 0.f);
      t = v / Sb[gi * WC + gj];
      if (r >= 7 && cc >= 7) cb[gi * WC + gj] = v;
    }
    tin[r][cc] = t;
  }
  __syncthreads();
  for (int idx = tid; idx < 39 * 32; idx += 256) {
    int r = idx >> 5, j = idx & 31;
    float s = 0.f;
    #pragma unroll
    for (int d = 0; d < 8; ++d) s += tin[r][j + d];
    hs[r][j] = s;
  }
  __syncthreads();
  for (int idx = tid; idx < 32 * 32; idx += 256) {
    int i = idx >> 5, j = idx & 31;
    size_t gofs = (size_t)b * NIMG + (i0 + i) * W + (j0 + j);
    float s = 0.f;
    #pragma unroll
    for (int d = 0; d < 8; ++d) s += hs[i + d][j];
    R[gofs] = E[gofs] * s;
  }
}

extern "C" void kernel_launch(void* const* d_in, const int* in_sizes, int n_in,
                              void* d_out, int out_size, void* d_ws, size_t ws_size,
                              hipStream_t stream) {
  const float* x   = (const float*)d_in[0];
  const float* w1  = (const float*)d_in[1];
  const float* w2  = (const float*)d_in[3];
  const float* g1  = (const float*)d_in[5];
  const float* be1 = (const float*)d_in[6];
  const float* g2  = (const float*)d_in[7];
  const float* be2 = (const float*)d_in[8];

  float* out_c = (float*)d_out;          // C_out: NPIX floats
  float* out_r = out_c + NPIX;           // R: NM floats

  // workspace: p_t 43.9 MB + Epart 11.5 + E 1.6 + S/y2 0.8 + ypart 0.23 ≈ 58 MB
  unsigned short* p_t = (unsigned short*)d_ws;          // [7][NPIX][8] bf16
  float* fbase = (float*)(p_t + (size_t)7 * NPIX * 8);
  size_t off = 0;
  float* Epart  = fbase + off; off += (size_t)7 * NM;
  float* E      = fbase + off; off += NM;
  float* Sarr   = fbase + off; off += NPIX;
  float* y2     = fbase + off; off += NPIX;
  float* ypart  = fbase + off; off += (size_t)NGRID * 112;
  float* stats2 = fbase + off; off += 128;
  float* ac     = fbase + off; off += 112;
  float* a2c2   = fbase + off; off += 2;

  hipMemsetAsync(stats2, 0, 128 * sizeof(float), stream);

  pool32_kernel<<<100 * B * 7, 256, 0, stream>>>(x, Epart, p_t);

  dim3 sg(10, 10, B);
  se_pool_kernel<<<sg, 256, 0, stream>>>(Epart, E, Sarr);

  y1_stats_kernel<<<NGRID, 256, 0, stream>>>(p_t, w1, ypart);
  ypart_bn1_kernel<<<1, 128, 0, stream>>>(ypart, g1, be1, ac);
  y2_kernel<<<NGRID, 256, 0, stream>>>(p_t, w1, ac, w2, y2, stats2);
  bn2_final_kernel<<<1, 64, 0, stream>>>(stats2, g2, be2, a2c2);

  dim3 rg(10, 10, B);
  r_pool_kernel<<<rg, 256, 0, stream>>>(y2, Sarr, a2c2, E, out_c, out_r);
}

// Round 14
// 107.259 us; speedup vs baseline: 1.7398x; 1.1024x over previous
//
#include <hip/hip_runtime.h>
#include <math.h>

#define B 4
#define C 56
#define H 320
#define W 320
#define HC 313
#define WC 313
#define NIMG (H*W)          // 102400
#define NSP  (HC*WC)        // 97969
#define NPIX (B*NSP)        // 391876
#define NM   (B*NIMG)       // 409600
#define BN_EPS 1e-5f
#define NGRID 512           // y1/y2 grid (R11-proven; 1536/3062 regress)

// pool32 tile: 32x32 interior, 39x39 halo
#define PHR 39
#define NF4 390             // 39 rows x 10 float4 = whole tin incl. pad col

typedef __attribute__((ext_vector_type(8))) short short8;
typedef __attribute__((ext_vector_type(16))) float float16;
typedef __attribute__((ext_vector_type(4))) float f32x4;

__device__ __forceinline__ unsigned short f2bf(float v) {
  unsigned int u = __float_as_uint(v);
  return (unsigned short)((u + 0x7fffu + ((u >> 16) & 1u)) >> 16);
}

// ---------------------------------------------------------------------------
// pool32 (R12/R13-verified math; NEW: 2 channels per barrier pair -> 8
// barriers/block instead of 16). float4 halo staging, esum in registers.
// p_t layout: [g][pix][8 ch] bf16 (R5-verified).
// ---------------------------------------------------------------------------
__global__ __launch_bounds__(256) void pool32_kernel(
    const float* __restrict__ x, float* __restrict__ Epart,
    unsigned short* __restrict__ p_t) {
  __shared__ float tin[2][PHR][40];         // 12480 B
  __shared__ float hs[2][PHR][32];          //  9984 B
  __shared__ unsigned short Pt[8][1024];    // 16384 B  (38.8 KB total)
  const int tid = threadIdx.x;
  int bid = blockIdx.x;
  const int g = bid % 7; bid /= 7;
  const int b = bid & 3; bid >>= 2;
  const int ty = bid / 10, tx = bid - (bid / 10) * 10;
  const int i0 = ty * 32, j0 = tx * 32;
  const float* xg = x + ((size_t)b * C + g * 8) * NIMG;

  // per-thread float4 halo slots (constant across channels)
  int r4[2], q4[2]; bool act[2], vld[2], inter[2]; size_t xoff[2];
  #pragma unroll
  for (int k = 0; k < 2; ++k) {
    int idx = tid + k * 256;
    r4[k] = idx / 10; q4[k] = idx - r4[k] * 10;
    act[k] = idx < NF4;
    vld[k] = act[k] && (i0 + r4[k] < H) && (j0 + q4[k] * 4 < W);
    inter[k] = act[k] && r4[k] < 32 && q4[k] < 8;   // fully-interior float4
    xoff[k] = (size_t)(i0 + r4[k]) * W + j0 + q4[k] * 4;
  }
  f32x4 cur4[2][2], nxt4[2][2];   // [channel-within-pair][slot]
  #pragma unroll
  for (int c2 = 0; c2 < 2; ++c2)
    #pragma unroll
    for (int k = 0; k < 2; ++k)
      cur4[c2][k] = vld[k] ? *(const f32x4*)(xg + (size_t)c2 * NIMG + xoff[k])
                           : (f32x4){0.f, 0.f, 0.f, 0.f};

  f32x4 esum4[2] = {{0.f, 0.f, 0.f, 0.f}, {0.f, 0.f, 0.f, 0.f}};

  #pragma unroll
  for (int cc = 0; cc < 8; cc += 2) {
    // stage both channels; esum from registers
    #pragma unroll
    for (int k = 0; k < 2; ++k) {
      if (act[k]) {
        *(f32x4*)&tin[0][r4[k]][q4[k] * 4] = cur4[0][k];
        *(f32x4*)&tin[1][r4[k]][q4[k] * 4] = cur4[1][k];
      }
      if (inter[k]) esum4[k] += cur4[0][k] + cur4[1][k];
    }
    __syncthreads();   // tin ready; prev vsum hs-reads done
    if (cc < 6) {
      #pragma unroll
      for (int c2 = 0; c2 < 2; ++c2)
        #pragma unroll
        for (int k = 0; k < 2; ++k)
          nxt4[c2][k] = vld[k]
              ? *(const f32x4*)(xg + (size_t)(cc + 2 + c2) * NIMG + xoff[k])
              : (f32x4){0.f, 0.f, 0.f, 0.f};
    }
    // horizontal 8-sums: 2 x 39 x 32 = 2496 items
    #pragma unroll
    for (int it = 0; it < 10; ++it) {
      int idx = tid + it * 256;
      if (idx < 2 * PHR * 32) {
        int ch = idx >= PHR * 32;
        int rem = idx - ch * PHR * 32;
        int r = rem >> 5, j = rem & 31;
        float s = 0.f;
        #pragma unroll
        for (int d = 0; d < 8; ++d) s += tin[ch][r][j + d];
        hs[ch][r][j] = s;
      }
    }
    __syncthreads();   // hs ready
    // vertical 8-sums -> Pt (bf16): 2 x 1024 = 2048 items
    #pragma unroll
    for (int it = 0; it < 8; ++it) {
      int idx = tid + it * 256;
      int ch = idx >> 10, pl = idx & 1023;
      int i = pl >> 5, j = pl & 31;
      float s = 0.f;
      #pragma unroll
      for (int d = 0; d < 8; ++d) s += hs[ch][i + d][j];
      Pt[cc + ch][pl] = f2bf(s * (1.f / 64.f));
    }
    #pragma unroll
    for (int c2 = 0; c2 < 2; ++c2)
      #pragma unroll
      for (int k = 0; k < 2; ++k) cur4[c2][k] = nxt4[c2][k];
  }
  __syncthreads();   // Pt complete

  // Epart: vectorized plain stores (each interior float4 owned by one block)
  float* Eb = Epart + ((size_t)g * B + b) * NIMG;
  #pragma unroll
  for (int k = 0; k < 2; ++k)
    if (inter[k]) *(f32x4*)&Eb[(i0 + r4[k]) * W + j0 + q4[k] * 4] = esum4[k];

  // p_t dump: 16B per valid pixel, coalesced (R5-verified)
  unsigned short* pg = p_t + (size_t)g * NPIX * 8;
  #pragma unroll
  for (int k = 0; k < 4; ++k) {
    int idx = tid + k * 256;
    int i = idx >> 5, j = idx & 31;
    int gi = i0 + i, gj = j0 + j;
    if (gi < HC && gj < WC) {
      unsigned short t8[8];
      #pragma unroll
      for (int c2 = 0; c2 < 8; ++c2) t8[c2] = Pt[c2][idx];
      *(short8*)(pg + ((size_t)b * NSP + gi * WC + gj) * 8) = *(short8*)t8;
    }
  }
}

// ---------------------------------------------------------------------------
// se_pool (R5-verified, verbatim)
// ---------------------------------------------------------------------------
__global__ __launch_bounds__(256) void se_pool_kernel(
    const float* __restrict__ Epart, float* __restrict__ E, float* __restrict__ S) {
  __shared__ float tin[39][40];
  __shared__ float hs[39][33];
  const int b = blockIdx.z;
  const int i0 = blockIdx.y * 32, j0 = blockIdx.x * 32;
  const int tid = threadIdx.x;
  for (int idx = tid; idx < 39 * 39; idx += 256) {
    int r = idx / 39, cc = idx - r * 39;
    int gi = i0 + r, gj = j0 + cc;
    float v = 0.f;
    if (gi < H && gj < W) {
      float s = 0.f;
      #pragma unroll
      for (int g = 0; g < 7; ++g)
        s += Epart[((size_t)g * B + b) * NIMG + gi * W + gj];
      v = expf(s * (1.f / C));
      if (r < 32 && cc < 32) E[(size_t)b * NIMG + gi * W + gj] = v;
    }
    tin[r][cc] = v;
  }
  __syncthreads();
  for (int idx = tid; idx < 39 * 32; idx += 256) {
    int r = idx >> 5, j = idx & 31;
    float s = 0.f;
    #pragma unroll
    for (int d = 0; d < 8; ++d) s += tin[r][j + d];
    hs[r][j] = s;
  }
  __syncthreads();
  for (int idx = tid; idx < 32 * 32; idx += 256) {
    int i = idx >> 5, j = idx & 31;
    int gi = i0 + i, gj = j0 + j;
    if (gi < HC && gj < WC) {
      float s = 0.f;
      #pragma unroll
      for (int d = 0; d < 8; ++d) s += hs[i + d][j];
      S[(size_t)b * NSP + gi * WC + gj] = s;
    }
  }
}

// ---------------------------------------------------------------------------
// y1_stats (R11-verified, verbatim: 512 blocks, 6 chunks, register s1/s2,
// plain-store 112-float partials per block).
// ---------------------------------------------------------------------------
__global__ __launch_bounds__(256) void y1_stats_kernel(
    const unsigned short* __restrict__ p_t, const float* __restrict__ w1,
    float* __restrict__ ypart) {
  __shared__ unsigned short Wl[64 * 64];
  __shared__ float red[4][32][64];   // 32 KB, used only in flush
  const int tid = threadIdx.x, wave = tid >> 6, lane = tid & 63;
  for (int idx = tid; idx < 4096; idx += 256) {
    int o = idx >> 6, k = idx & 63;
    float v = (o < C && k < C) ? w1[o * C + k] : 0.f;
    *(unsigned short*)((char*)Wl + (o * 128 + ((2 * k) ^ ((o & 7) << 4)))) = f2bf(v);
  }
  __syncthreads();
  short8 afr[2][4];
  #pragma unroll
  for (int q = 0; q < 2; ++q)
    #pragma unroll
    for (int ks = 0; ks < 4; ++ks) {
      int row = q * 32 + (lane & 31), kb = ks * 16 + 8 * (lane >> 5);
      afr[q][ks] = *(const short8*)((const char*)Wl + row * 128 + ((2 * kb) ^ ((row & 7) << 4)));
    }
  float s1[2][16], s2[2][16];
  #pragma unroll
  for (int q = 0; q < 2; ++q)
    #pragma unroll
    for (int r = 0; r < 16; ++r) { s1[q][r] = 0.f; s2[q][r] = 0.f; }

  const int h = lane >> 5;
  const int nchunk = (NPIX + 127) / 128;   // 3062
  for (int ch = blockIdx.x; ch < nchunk; ch += NGRID) {
    int col = ch * 128 + wave * 32 + (lane & 31);
    bool cv = col < NPIX;
    size_t pofs = (size_t)(cv ? col : 0) * 8;
    short8 bfr[4];
    #pragma unroll
    for (int ks = 0; ks < 4; ++ks) {
      int g = ks * 2 + h;
      short8 bv = (short8){0, 0, 0, 0, 0, 0, 0, 0};
      if (g < 7 && cv) bv = *(const short8*)(p_t + (size_t)g * NPIX * 8 + pofs);
      bfr[ks] = bv;
    }
    float16 a0 = {}, a1 = {};
    #pragma unroll
    for (int ks = 0; ks < 4; ++ks) {
      a0 = __builtin_amdgcn_mfma_f32_32x32x16_bf16(afr[0][ks], bfr[ks], a0, 0, 0, 0);
      a1 = __builtin_amdgcn_mfma_f32_32x32x16_bf16(afr[1][ks], bfr[ks], a1, 0, 0, 0);
    }
    #pragma unroll
    for (int r = 0; r < 16; ++r) {
      s1[0][r] += a0[r]; s2[0][r] = fmaf(a0[r], a0[r], s2[0][r]);
      s1[1][r] += a1[r]; s2[1][r] = fmaf(a1[r], a1[r], s2[1][r]);
    }
  }
  // flush: pass 0 = sums, pass 1 = sumsq (R11-verified mapping)
  for (int pass = 0; pass < 2; ++pass) {
    __syncthreads();
    #pragma unroll
    for (int q = 0; q < 2; ++q)
      #pragma unroll
      for (int r = 0; r < 16; ++r)
        red[wave][q * 16 + r][lane] = pass ? s2[q][r] : s1[q][r];
    __syncthreads();
    if (tid < C) {
      int row = tid, q = row >> 5, rr = row & 31;
      int hh = (rr >> 2) & 1, reg = (rr & 3) | ((rr >> 3) << 2);
      float s = 0.f;
      #pragma unroll
      for (int w = 0; w < 4; ++w)
        #pragma unroll
        for (int cl = 0; cl < 32; ++cl)
          s += red[w][q * 16 + reg][32 * hh + cl];
      ypart[blockIdx.x * 112 + pass * 56 + row] = s;
    }
  }
}

// ---------------------------------------------------------------------------
// ypart_bn1 (R11-verified, verbatim): reduce 512 partials + BN1 coefficients.
// ---------------------------------------------------------------------------
__global__ void ypart_bn1_kernel(const float* __restrict__ ypart,
                                 const float* __restrict__ g1, const float* __restrict__ be1,
                                 float* __restrict__ ac) {
  __shared__ float sums[112];
  int t = threadIdx.x;   // 128 threads
  if (t < 112) {
    float s0 = 0.f, s1 = 0.f, s2 = 0.f, s3 = 0.f;
    #pragma unroll 4
    for (int b = 0; b < NGRID; b += 4) {
      s0 += ypart[(b + 0) * 112 + t];
      s1 += ypart[(b + 1) * 112 + t];
      s2 += ypart[(b + 2) * 112 + t];
      s3 += ypart[(b + 3) * 112 + t];
    }
    sums[t] = (s0 + s1) + (s2 + s3);
  }
  __syncthreads();
  if (t < C) {
    float m = sums[t] * (1.f / NPIX);
    float var = sums[56 + t] * (1.f / NPIX) - m * m;
    float a = g1[t] * rsqrtf(var + BN_EPS);
    ac[t] = a;
    ac[C + t] = fmaf(-a, m, be1[t]);
  }
}

// ---------------------------------------------------------------------------
// y2 (R11-verified body, 512 blocks): d2 = w2 . relu(af*(W1 p) + cf).
// NEW: BN2 partials plain-stored per wave to y2part (no atomics, no memset).
// ---------------------------------------------------------------------------
__global__ __launch_bounds__(256) void y2_kernel(
    const unsigned short* __restrict__ p_t, const float* __restrict__ w1,
    const float* __restrict__ ac, const float* __restrict__ w2,
    float* __restrict__ y2, float* __restrict__ y2part) {
  __shared__ unsigned short Wl[64 * 64];
  __shared__ float af[64], cf[64], wf[64];
  const int tid = threadIdx.x, wave = tid >> 6, lane = tid & 63;
  for (int idx = tid; idx < 4096; idx += 256) {
    int o = idx >> 6, k = idx & 63;
    float v = (o < C && k < C) ? w1[o * C + k] : 0.f;
    *(unsigned short*)((char*)Wl + (o * 128 + ((2 * k) ^ ((o & 7) << 4)))) = f2bf(v);
  }
  if (tid < 64) {
    bool ok = tid < C;
    af[tid] = ok ? ac[tid] : 0.f;
    cf[tid] = ok ? ac[C + tid] : 0.f;
    wf[tid] = ok ? w2[tid] : 0.f;
  }
  __syncthreads();
  short8 afr[2][4];
  #pragma unroll
  for (int q = 0; q < 2; ++q)
    #pragma unroll
    for (int ks = 0; ks < 4; ++ks) {
      int row = q * 32 + (lane & 31), kb = ks * 16 + 8 * (lane >> 5);
      afr[q][ks] = *(const short8*)((const char*)Wl + row * 128 + ((2 * kb) ^ ((row & 7) << 4)));
    }
  const int h = lane >> 5;
  float ss1 = 0.f, ss2 = 0.f;
  const int nchunk = (NPIX + 127) / 128;
  for (int ch = blockIdx.x; ch < nchunk; ch += NGRID) {
    int col = ch * 128 + wave * 32 + (lane & 31);
    bool cv = col < NPIX;
    size_t pofs = (size_t)(cv ? col : 0) * 8;
    short8 bfr[4];
    #pragma unroll
    for (int ks = 0; ks < 4; ++ks) {
      int g = ks * 2 + h;
      short8 bv = (short8){0, 0, 0, 0, 0, 0, 0, 0};
      if (g < 7 && cv) bv = *(const short8*)(p_t + (size_t)g * NPIX * 8 + pofs);
      bfr[ks] = bv;
    }
    float16 a0 = {}, a1 = {};
    #pragma unroll
    for (int ks = 0; ks < 4; ++ks) {
      a0 = __builtin_amdgcn_mfma_f32_32x32x16_bf16(afr[0][ks], bfr[ks], a0, 0, 0, 0);
      a1 = __builtin_amdgcn_mfma_f32_32x32x16_bf16(afr[1][ks], bfr[ks], a1, 0, 0, 0);
    }
    float ysum = 0.f;
    #pragma unroll
    for (int r = 0; r < 16; ++r) {
      int o0 = (r & 3) + 8 * (r >> 2) + 4 * h;
      ysum = fmaf(wf[o0], fmaxf(fmaf(af[o0], a0[r], cf[o0]), 0.f), ysum);
      int o1 = o0 + 32;
      ysum = fmaf(wf[o1], fmaxf(fmaf(af[o1], a1[r], cf[o1]), 0.f), ysum);
    }
    ysum += __shfl_xor(ysum, 32);
    bool wr = cv && lane < 32;
    if (wr) {
      y2[col] = ysum;
      ss1 += ysum;
      ss2 = fmaf(ysum, ysum, ss2);
    }
  }
  #pragma unroll
  for (int off = 1; off < 64; off <<= 1) {
    ss1 += __shfl_xor(ss1, off);
    ss2 += __shfl_xor(ss2, off);
  }
  if (lane == 0) {
    y2part[(blockIdx.x * 4 + wave) * 2 + 0] = ss1;
    y2part[(blockIdx.x * 4 + wave) * 2 + 1] = ss2;
  }
}

// bn2_final: reduce 2048 per-wave partial pairs (plain loads) + BN2 coeffs
__global__ void bn2_final_kernel(const float* __restrict__ y2part,
                                 const float* __restrict__ g2, const float* __restrict__ be2,
                                 float* __restrict__ a2c2) {
  __shared__ float red[8];
  int t = threadIdx.x;   // 256 threads
  float s1 = 0.f, s2 = 0.f;
  for (int i = t; i < NGRID * 4; i += 256) {
    s1 += y2part[i * 2 + 0];
    s2 += y2part[i * 2 + 1];
  }
  #pragma unroll
  for (int off = 32; off > 0; off >>= 1) {
    s1 += __shfl_down(s1, off);
    s2 += __shfl_down(s2, off);
  }
  int wave = t >> 6, lane = t & 63;
  if (lane == 0) { red[wave * 2] = s1; red[wave * 2 + 1] = s2; }
  __syncthreads();
  if (t == 0) {
    s1 = red[0] + red[2] + red[4] + red[6];
    s2 = red[1] + red[3] + red[5] + red[7];
    float mean = s1 * (1.f / NPIX);
    float var  = s2 * (1.f / NPIX) - mean * mean;
    float a = g2[0] * rsqrtf(var + BN_EPS);
    a2c2[0] = a;
    a2c2[1] = fmaf(-a, mean, be2[0]);
  }
}

// ---------------------------------------------------------------------------
// r_pool (R5-verified, verbatim)
// ---------------------------------------------------------------------------
__global__ __launch_bounds__(256) void r_pool_kernel(
    const float* __restrict__ y2, const float* __restrict__ S,
    const float* __restrict__ a2c2, const float* __restrict__ E,
    float* __restrict__ cout, float* __restrict__ R) {
  __shared__ float tin[39][40];
  __shared__ float hs[39][33];
  const int b = blockIdx.z;
  const int i0 = blockIdx.y * 32, j0 = blockIdx.x * 32;
  const int tid = threadIdx.x;
  const float a2 = a2c2[0], c2 = a2c2[1];
  const float* y2b = y2 + (size_t)b * NSP;
  const float* Sb  = S + (size_t)b * NSP;
  float* cb = cout + (size_t)b * NSP;
  for (int idx = tid; idx < 39 * 39; idx += 256) {
    int r = idx / 39, cc = idx - r * 39;
    int gi = i0 + r - 7, gj = j0 + cc - 7;
    float t = 0.f;
    if (gi >= 0 && gi < HC && gj >= 0 && gj < WC) {
      float v = fmaxf(fmaf(a2, y2b[gi * WC + gj], c2), 0.f);
      t = v / Sb[gi * WC + gj];
      if (r >= 7 && cc >= 7) cb[gi * WC + gj] = v;
    }
    tin[r][cc] = t;
  }
  __syncthreads();
  for (int idx = tid; idx < 39 * 32; idx += 256) {
    int r = idx >> 5, j = idx & 31;
    float s = 0.f;
    #pragma unroll
    for (int d = 0; d < 8; ++d) s += tin[r][j + d];
    hs[r][j] = s;
  }
  __syncthreads();
  for (int idx = tid; idx < 32 * 32; idx += 256) {
    int i = idx >> 5, j = idx & 31;
    size_t gofs = (size_t)b * NIMG + (i0 + i) * W + (j0 + j);
    float s = 0.f;
    #pragma unroll
    for (int d = 0; d < 8; ++d) s += hs[i + d][j];
    R[gofs] = E[gofs] * s;
  }
}

extern "C" void kernel_launch(void* const* d_in, const int* in_sizes, int n_in,
                              void* d_out, int out_size, void* d_ws, size_t ws_size,
                              hipStream_t stream) {
  const float* x   = (const float*)d_in[0];
  const float* w1  = (const float*)d_in[1];
  const float* w2  = (const float*)d_in[3];
  const float* g1  = (const float*)d_in[5];
  const float* be1 = (const float*)d_in[6];
  const float* g2  = (const float*)d_in[7];
  const float* be2 = (const float*)d_in[8];

  float* out_c = (float*)d_out;          // C_out: NPIX floats
  float* out_r = out_c + NPIX;           // R: NM floats

  // workspace: p_t 43.9 MB + Epart 11.5 + E 1.6 + S/y2 0.8 + small ≈ 58 MB
  unsigned short* p_t = (unsigned short*)d_ws;          // [7][NPIX][8] bf16
  float* fbase = (float*)(p_t + (size_t)7 * NPIX * 8);
  size_t off = 0;
  float* Epart  = fbase + off; off += (size_t)7 * NM;
  float* E      = fbase + off; off += NM;
  float* Sarr   = fbase + off; off += NPIX;
  float* y2     = fbase + off; off += NPIX;
  float* ypart  = fbase + off; off += (size_t)NGRID * 112;
  float* y2part = fbase + off; off += (size_t)NGRID * 8;
  float* ac     = fbase + off; off += 112;
  float* a2c2   = fbase + off; off += 2;

  pool32_kernel<<<100 * B * 7, 256, 0, stream>>>(x, Epart, p_t);

  dim3 sg(10, 10, B);
  se_pool_kernel<<<sg, 256, 0, stream>>>(Epart, E, Sarr);

  y1_stats_kernel<<<NGRID, 256, 0, stream>>>(p_t, w1, ypart);
  ypart_bn1_kernel<<<1, 128, 0, stream>>>(ypart, g1, be1, ac);
  y2_kernel<<<NGRID, 256, 0, stream>>>(p_t, w1, ac, w2, y2, y2part);
  bn2_final_kernel<<<1, 256, 0, stream>>>(y2part, g2, be2, a2c2);

  dim3 rg(10, 10, B);
  r_pool_kernel<<<rg, 256, 0, stream>>>(y2, Sarr, a2c2, E, out_c, out_r);
}

// Round 15
// 104.837 us; speedup vs baseline: 1.7800x; 1.0231x over previous
//
#include <hip/hip_runtime.h>
#include <math.h>

#define B 4
#define C 56
#define H 320
#define W 320
#define HC 313
#define WC 313
#define NIMG (H*W)          // 102400
#define NSP  (HC*WC)        // 97969
#define NPIX (B*NSP)        // 391876
#define NM   (B*NIMG)       // 409600
#define BN_EPS 1e-5f
#define NGRID 512           // y1/y2 grid (R11-proven; 1536/3062 regress)

// pool32 tile: 32x32 interior, 39x39 halo
#define PHR 39
#define NF4 390             // 39 rows x 10 float4 = whole tin incl. pad col

typedef __attribute__((ext_vector_type(8))) short short8;
typedef __attribute__((ext_vector_type(16))) float float16;
typedef __attribute__((ext_vector_type(4))) float f32x4;
typedef __attribute__((ext_vector_type(4))) unsigned short u16x4;

__device__ __forceinline__ unsigned short f2bf(float v) {
  unsigned int u = __float_as_uint(v);
  return (unsigned short)((u + 0x7fffu + ((u >> 16) & 1u)) >> 16);
}

// ---------------------------------------------------------------------------
// pool32 v3: R13 1-ch/round structure + VECTORIZED hsum/vsum (f32x4 LDS ops,
// ~3x fewer LDS instructions — R14 showed LDS-issue-bound). float4 staging,
// esum in registers. p_t layout: [g][pix][8 ch] bf16 (R5-verified).
// hsum sliding window: s[j+1] = s[j] - t[j] + t[j+8].
// ---------------------------------------------------------------------------
__global__ __launch_bounds__(256) void pool32_kernel(
    const float* __restrict__ x, float* __restrict__ Epart,
    unsigned short* __restrict__ p_t) {
  __shared__ float tin[PHR][40];            // 6240 B
  __shared__ float hs[PHR][40];             // 6240 B (pad 40: bank-offset 8/row)
  __shared__ unsigned short Pt[8][1024];    // 16384 B  (28.9 KB total)
  const int tid = threadIdx.x;
  int bid = blockIdx.x;
  const int g = bid % 7; bid /= 7;
  const int b = bid & 3; bid >>= 2;
  const int ty = bid / 10, tx = bid - (bid / 10) * 10;
  const int i0 = ty * 32, j0 = tx * 32;
  const float* xg = x + ((size_t)b * C + g * 8) * NIMG;

  // per-thread float4 halo slots (constant across channels)
  int r4[2], q4[2]; bool act[2], vld[2], inter[2]; size_t xoff[2];
  #pragma unroll
  for (int k = 0; k < 2; ++k) {
    int idx = tid + k * 256;
    r4[k] = idx / 10; q4[k] = idx - r4[k] * 10;
    act[k] = idx < NF4;
    vld[k] = act[k] && (i0 + r4[k] < H) && (j0 + q4[k] * 4 < W);
    inter[k] = act[k] && r4[k] < 32 && q4[k] < 8;   // fully-interior float4
    xoff[k] = (size_t)(i0 + r4[k]) * W + j0 + q4[k] * 4;
  }
  f32x4 cur4[2], nxt4[2];
  #pragma unroll
  for (int k = 0; k < 2; ++k)
    cur4[k] = vld[k] ? *(const f32x4*)(xg + xoff[k]) : (f32x4){0.f, 0.f, 0.f, 0.f};

  f32x4 esum4[2] = {{0.f, 0.f, 0.f, 0.f}, {0.f, 0.f, 0.f, 0.f}};

  // hsum/vsum task coordinates (fixed across channels)
  const int hr = tid >> 3, hg = (tid & 7) * 4;          // hsum round 1: rows 0..31
  const int hr2 = (tid + 256) >> 3;                     // hsum round 2: rows 32..38
  const bool h2 = tid < (PHR * 8 - 256);                // 56 threads
  const int vi = tid >> 3, vg = (tid & 7) * 4;          // vsum: 32 rows x 8 groups

  #pragma unroll
  for (int c = 0; c < 8; ++c) {
    #pragma unroll
    for (int k = 0; k < 2; ++k) {
      if (act[k]) *(f32x4*)&tin[r4[k]][q4[k] * 4] = cur4[k];
      if (inter[k]) esum4[k] += cur4[k];
    }
    __syncthreads();   // tin ready; prev vsum hs-reads done
    if (c < 7) {
      const float* xp = xg + (size_t)(c + 1) * NIMG;
      #pragma unroll
      for (int k = 0; k < 2; ++k)
        nxt4[k] = vld[k] ? *(const f32x4*)(xp + xoff[k]) : (f32x4){0.f, 0.f, 0.f, 0.f};
    }
    // horizontal 8-sums, 4 outputs/task via sliding window
    {
      f32x4 a  = *(const f32x4*)&tin[hr][hg];
      f32x4 bv = *(const f32x4*)&tin[hr][hg + 4];
      f32x4 cv = *(const f32x4*)&tin[hr][hg + 8];
      float s0 = ((a[0] + a[1]) + (a[2] + a[3])) + ((bv[0] + bv[1]) + (bv[2] + bv[3]));
      float s1 = s0 - a[0] + cv[0];
      float s2 = s1 - a[1] + cv[1];
      float s3 = s2 - a[2] + cv[2];
      *(f32x4*)&hs[hr][hg] = (f32x4){s0, s1, s2, s3};
      if (h2) {
        f32x4 a2  = *(const f32x4*)&tin[hr2][hg];
        f32x4 b2  = *(const f32x4*)&tin[hr2][hg + 4];
        f32x4 c2  = *(const f32x4*)&tin[hr2][hg + 8];
        float t0 = ((a2[0] + a2[1]) + (a2[2] + a2[3])) + ((b2[0] + b2[1]) + (b2[2] + b2[3]));
        float t1 = t0 - a2[0] + c2[0];
        float t2 = t1 - a2[1] + c2[1];
        float t3 = t2 - a2[2] + c2[2];
        *(f32x4*)&hs[hr2][hg] = (f32x4){t0, t1, t2, t3};
      }
    }
    __syncthreads();   // hs ready
    // vertical 8-sums -> Pt (bf16), 4 outputs/task
    {
      f32x4 s = *(const f32x4*)&hs[vi][vg];
      #pragma unroll
      for (int d = 1; d < 8; ++d) s += *(const f32x4*)&hs[vi + d][vg];
      u16x4 o;
      #pragma unroll
      for (int k = 0; k < 4; ++k) o[k] = f2bf(s[k] * (1.f / 64.f));
      *(u16x4*)&Pt[c][vi * 32 + vg] = o;
    }
    #pragma unroll
    for (int k = 0; k < 2; ++k) cur4[k] = nxt4[k];
  }
  __syncthreads();   // Pt complete

  // Epart: vectorized plain stores (each interior float4 owned by one block)
  float* Eb = Epart + ((size_t)g * B + b) * NIMG;
  #pragma unroll
  for (int k = 0; k < 2; ++k)
    if (inter[k]) *(f32x4*)&Eb[(i0 + r4[k]) * W + j0 + q4[k] * 4] = esum4[k];

  // p_t dump: 16B per valid pixel, coalesced (R5-verified)
  unsigned short* pg = p_t + (size_t)g * NPIX * 8;
  #pragma unroll
  for (int k = 0; k < 4; ++k) {
    int idx = tid + k * 256;
    int i = idx >> 5, j = idx & 31;
    int gi = i0 + i, gj = j0 + j;
    if (gi < HC && gj < WC) {
      unsigned short t8[8];
      #pragma unroll
      for (int c2 = 0; c2 < 8; ++c2) t8[c2] = Pt[c2][idx];
      *(short8*)(pg + ((size_t)b * NSP + gi * WC + gj) * 8) = *(short8*)t8;
    }
  }
}

// ---------------------------------------------------------------------------
// se_pool (R5-verified, verbatim)
// ---------------------------------------------------------------------------
__global__ __launch_bounds__(256) void se_pool_kernel(
    const float* __restrict__ Epart, float* __restrict__ E, float* __restrict__ S) {
  __shared__ float tin[39][40];
  __shared__ float hs[39][33];
  const int b = blockIdx.z;
  const int i0 = blockIdx.y * 32, j0 = blockIdx.x * 32;
  const int tid = threadIdx.x;
  for (int idx = tid; idx < 39 * 39; idx += 256) {
    int r = idx / 39, cc = idx - r * 39;
    int gi = i0 + r, gj = j0 + cc;
    float v = 0.f;
    if (gi < H && gj < W) {
      float s = 0.f;
      #pragma unroll
      for (int g = 0; g < 7; ++g)
        s += Epart[((size_t)g * B + b) * NIMG + gi * W + gj];
      v = expf(s * (1.f / C));
      if (r < 32 && cc < 32) E[(size_t)b * NIMG + gi * W + gj] = v;
    }
    tin[r][cc] = v;
  }
  __syncthreads();
  for (int idx = tid; idx < 39 * 32; idx += 256) {
    int r = idx >> 5, j = idx & 31;
    float s = 0.f;
    #pragma unroll
    for (int d = 0; d < 8; ++d) s += tin[r][j + d];
    hs[r][j] = s;
  }
  __syncthreads();
  for (int idx = tid; idx < 32 * 32; idx += 256) {
    int i = idx >> 5, j = idx & 31;
    int gi = i0 + i, gj = j0 + j;
    if (gi < HC && gj < WC) {
      float s = 0.f;
      #pragma unroll
      for (int d = 0; d < 8; ++d) s += hs[i + d][j];
      S[(size_t)b * NSP + gi * WC + gj] = s;
    }
  }
}

// ---------------------------------------------------------------------------
// y1_stats (R11-verified math; NEW: next-chunk register prefetch to hide
// load latency at 2 blocks/CU). Plain-store 112-float partials per block.
// ---------------------------------------------------------------------------
__global__ __launch_bounds__(256) void y1_stats_kernel(
    const unsigned short* __restrict__ p_t, const float* __restrict__ w1,
    float* __restrict__ ypart) {
  __shared__ unsigned short Wl[64 * 64];
  __shared__ float red[4][32][64];   // 32 KB, used only in flush
  const int tid = threadIdx.x, wave = tid >> 6, lane = tid & 63;
  for (int idx = tid; idx < 4096; idx += 256) {
    int o = idx >> 6, k = idx & 63;
    float v = (o < C && k < C) ? w1[o * C + k] : 0.f;
    *(unsigned short*)((char*)Wl + (o * 128 + ((2 * k) ^ ((o & 7) << 4)))) = f2bf(v);
  }
  __syncthreads();
  short8 afr[2][4];
  #pragma unroll
  for (int q = 0; q < 2; ++q)
    #pragma unroll
    for (int ks = 0; ks < 4; ++ks) {
      int row = q * 32 + (lane & 31), kb = ks * 16 + 8 * (lane >> 5);
      afr[q][ks] = *(const short8*)((const char*)Wl + row * 128 + ((2 * kb) ^ ((row & 7) << 4)));
    }
  float s1[2][16], s2[2][16];
  #pragma unroll
  for (int q = 0; q < 2; ++q)
    #pragma unroll
    for (int r = 0; r < 16; ++r) { s1[q][r] = 0.f; s2[q][r] = 0.f; }

  const int h = lane >> 5;
  const int nchunk = (NPIX + 127) / 128;   // 3062
  auto loadch = [&](int cc, short8* dst) {
    int col = cc * 128 + wave * 32 + (lane & 31);
    bool cv = (cc < nchunk) && (col < NPIX);
    size_t pofs = (size_t)(cv ? col : 0) * 8;
    #pragma unroll
    for (int ks = 0; ks < 4; ++ks) {
      int gg = ks * 2 + h;
      short8 bv = (short8){0, 0, 0, 0, 0, 0, 0, 0};
      if (gg < 7 && cv) bv = *(const short8*)(p_t + (size_t)gg * NPIX * 8 + pofs);
      dst[ks] = bv;
    }
  };
  short8 bfr[4];
  loadch(blockIdx.x, bfr);
  for (int ch = blockIdx.x; ch < nchunk; ch += NGRID) {
    short8 nbfr[4];
    loadch(ch + NGRID, nbfr);
    float16 a0 = {}, a1 = {};
    #pragma unroll
    for (int ks = 0; ks < 4; ++ks) {
      a0 = __builtin_amdgcn_mfma_f32_32x32x16_bf16(afr[0][ks], bfr[ks], a0, 0, 0, 0);
      a1 = __builtin_amdgcn_mfma_f32_32x32x16_bf16(afr[1][ks], bfr[ks], a1, 0, 0, 0);
    }
    #pragma unroll
    for (int r = 0; r < 16; ++r) {
      s1[0][r] += a0[r]; s2[0][r] = fmaf(a0[r], a0[r], s2[0][r]);
      s1[1][r] += a1[r]; s2[1][r] = fmaf(a1[r], a1[r], s2[1][r]);
    }
    #pragma unroll
    for (int ks = 0; ks < 4; ++ks) bfr[ks] = nbfr[ks];
  }
  // flush: pass 0 = sums, pass 1 = sumsq (R11-verified mapping)
  for (int pass = 0; pass < 2; ++pass) {
    __syncthreads();
    #pragma unroll
    for (int q = 0; q < 2; ++q)
      #pragma unroll
      for (int r = 0; r < 16; ++r)
        red[wave][q * 16 + r][lane] = pass ? s2[q][r] : s1[q][r];
    __syncthreads();
    if (tid < C) {
      int row = tid, q = row >> 5, rr = row & 31;
      int hh = (rr >> 2) & 1, reg = (rr & 3) | ((rr >> 3) << 2);
      float s = 0.f;
      #pragma unroll
      for (int w = 0; w < 4; ++w)
        #pragma unroll
        for (int cl = 0; cl < 32; ++cl)
          s += red[w][q * 16 + reg][32 * hh + cl];
      ypart[blockIdx.x * 112 + pass * 56 + row] = s;
    }
  }
}

// ---------------------------------------------------------------------------
// ypart_bn1 (R11-verified, verbatim): reduce 512 partials + BN1 coefficients.
// ---------------------------------------------------------------------------
__global__ void ypart_bn1_kernel(const float* __restrict__ ypart,
                                 const float* __restrict__ g1, const float* __restrict__ be1,
                                 float* __restrict__ ac) {
  __shared__ float sums[112];
  int t = threadIdx.x;   // 128 threads
  if (t < 112) {
    float s0 = 0.f, s1 = 0.f, s2 = 0.f, s3 = 0.f;
    #pragma unroll 4
    for (int b = 0; b < NGRID; b += 4) {
      s0 += ypart[(b + 0) * 112 + t];
      s1 += ypart[(b + 1) * 112 + t];
      s2 += ypart[(b + 2) * 112 + t];
      s3 += ypart[(b + 3) * 112 + t];
    }
    sums[t] = (s0 + s1) + (s2 + s3);
  }
  __syncthreads();
  if (t < C) {
    float m = sums[t] * (1.f / NPIX);
    float var = sums[56 + t] * (1.f / NPIX) - m * m;
    float a = g1[t] * rsqrtf(var + BN_EPS);
    ac[t] = a;
    ac[C + t] = fmaf(-a, m, be1[t]);
  }
}

// ---------------------------------------------------------------------------
// y2 (R11-verified math; NEW: next-chunk register prefetch). BN2 partials
// plain-stored per wave to y2part (no atomics).
// ---------------------------------------------------------------------------
__global__ __launch_bounds__(256) void y2_kernel(
    const unsigned short* __restrict__ p_t, const float* __restrict__ w1,
    const float* __restrict__ ac, const float* __restrict__ w2,
    float* __restrict__ y2, float* __restrict__ y2part) {
  __shared__ unsigned short Wl[64 * 64];
  __shared__ float af[64], cf[64], wf[64];
  const int tid = threadIdx.x, wave = tid >> 6, lane = tid & 63;
  for (int idx = tid; idx < 4096; idx += 256) {
    int o = idx >> 6, k = idx & 63;
    float v = (o < C && k < C) ? w1[o * C + k] : 0.f;
    *(unsigned short*)((char*)Wl + (o * 128 + ((2 * k) ^ ((o & 7) << 4)))) = f2bf(v);
  }
  if (tid < 64) {
    bool ok = tid < C;
    af[tid] = ok ? ac[tid] : 0.f;
    cf[tid] = ok ? ac[C + tid] : 0.f;
    wf[tid] = ok ? w2[tid] : 0.f;
  }
  __syncthreads();
  short8 afr[2][4];
  #pragma unroll
  for (int q = 0; q < 2; ++q)
    #pragma unroll
    for (int ks = 0; ks < 4; ++ks) {
      int row = q * 32 + (lane & 31), kb = ks * 16 + 8 * (lane >> 5);
      afr[q][ks] = *(const short8*)((const char*)Wl + row * 128 + ((2 * kb) ^ ((row & 7) << 4)));
    }
  const int h = lane >> 5;
  float ss1 = 0.f, ss2 = 0.f;
  const int nchunk = (NPIX + 127) / 128;
  auto loadch = [&](int cc, short8* dst) {
    int col = cc * 128 + wave * 32 + (lane & 31);
    bool cv = (cc < nchunk) && (col < NPIX);
    size_t pofs = (size_t)(cv ? col : 0) * 8;
    #pragma unroll
    for (int ks = 0; ks < 4; ++ks) {
      int gg = ks * 2 + h;
      short8 bv = (short8){0, 0, 0, 0, 0, 0, 0, 0};
      if (gg < 7 && cv) bv = *(const short8*)(p_t + (size_t)gg * NPIX * 8 + pofs);
      dst[ks] = bv;
    }
  };
  short8 bfr[4];
  loadch(blockIdx.x, bfr);
  for (int ch = blockIdx.x; ch < nchunk; ch += NGRID) {
    short8 nbfr[4];
    loadch(ch + NGRID, nbfr);
    float16 a0 = {}, a1 = {};
    #pragma unroll
    for (int ks = 0; ks < 4; ++ks) {
      a0 = __builtin_amdgcn_mfma_f32_32x32x16_bf16(afr[0][ks], bfr[ks], a0, 0, 0, 0);
      a1 = __builtin_amdgcn_mfma_f32_32x32x16_bf16(afr[1][ks], bfr[ks], a1, 0, 0, 0);
    }
    float ysum = 0.f;
    #pragma unroll
    for (int r = 0; r < 16; ++r) {
      int o0 = (r & 3) + 8 * (r >> 2) + 4 * h;
      ysum = fmaf(wf[o0], fmaxf(fmaf(af[o0], a0[r], cf[o0]), 0.f), ysum);
      int o1 = o0 + 32;
      ysum = fmaf(wf[o1], fmaxf(fmaf(af[o1], a1[r], cf[o1]), 0.f), ysum);
    }
    ysum += __shfl_xor(ysum, 32);
    int col = ch * 128 + wave * 32 + (lane & 31);
    bool wr = (col < NPIX) && lane < 32;
    if (wr) {
      y2[col] = ysum;
      ss1 += ysum;
      ss2 = fmaf(ysum, ysum, ss2);
    }
    #pragma unroll
    for (int ks = 0; ks < 4; ++ks) bfr[ks] = nbfr[ks];
  }
  #pragma unroll
  for (int off = 1; off < 64; off <<= 1) {
    ss1 += __shfl_xor(ss1, off);
    ss2 += __shfl_xor(ss2, off);
  }
  if (lane == 0) {
    y2part[(blockIdx.x * 4 + wave) * 2 + 0] = ss1;
    y2part[(blockIdx.x * 4 + wave) * 2 + 1] = ss2;
  }
}

// bn2_final (R14-verified): reduce 2048 per-wave partial pairs + BN2 coeffs
__global__ void bn2_final_kernel(const float* __restrict__ y2part,
                                 const float* __restrict__ g2, const float* __restrict__ be2,
                                 float* __restrict__ a2c2) {
  __shared__ float red[8];
  int t = threadIdx.x;   // 256 threads
  float s1 = 0.f, s2 = 0.f;
  for (int i = t; i < NGRID * 4; i += 256) {
    s1 += y2part[i * 2 + 0];
    s2 += y2part[i * 2 + 1];
  }
  #pragma unroll
  for (int off = 32; off > 0; off >>= 1) {
    s1 += __shfl_down(s1, off);
    s2 += __shfl_down(s2, off);
  }
  int wave = t >> 6, lane = t & 63;
  if (lane == 0) { red[wave * 2] = s1; red[wave * 2 + 1] = s2; }
  __syncthreads();
  if (t == 0) {
    s1 = red[0] + red[2] + red[4] + red[6];
    s2 = red[1] + red[3] + red[5] + red[7];
    float mean = s1 * (1.f / NPIX);
    float var  = s2 * (1.f / NPIX) - mean * mean;
    float a = g2[0] * rsqrtf(var + BN_EPS);
    a2c2[0] = a;
    a2c2[1] = fmaf(-a, mean, be2[0]);
  }
}

// ---------------------------------------------------------------------------
// r_pool (R5-verified, verbatim)
// ---------------------------------------------------------------------------
__global__ __launch_bounds__(256) void r_pool_kernel(
    const float* __restrict__ y2, const float* __restrict__ S,
    const float* __restrict__ a2c2, const float* __restrict__ E,
    float* __restrict__ cout, float* __restrict__ R) {
  __shared__ float tin[39][40];
  __shared__ float hs[39][33];
  const int b = blockIdx.z;
  const int i0 = blockIdx.y * 32, j0 = blockIdx.x * 32;
  const int tid = threadIdx.x;
  const float a2 = a2c2[0], c2 = a2c2[1];
  const float* y2b = y2 + (size_t)b * NSP;
  const float* Sb  = S + (size_t)b * NSP;
  float* cb = cout + (size_t)b * NSP;
  for (int idx = tid; idx < 39 * 39; idx += 256) {
    int r = idx / 39, cc = idx - r * 39;
    int gi = i0 + r - 7, gj = j0 + cc - 7;
    float t = 0.f;
    if (gi >= 0 && gi < HC && gj >= 0 && gj < WC) {
      float v = fmaxf(fmaf(a2, y2b[gi * WC + gj], c2), 0.f);
      t = v / Sb[gi * WC + gj];
      if (r >= 7 && cc >= 7) cb[gi * WC + gj] = v;
    }
    tin[r][cc] = t;
  }
  __syncthreads();
  for (int idx = tid; idx < 39 * 32; idx += 256) {
    int r = idx >> 5, j = idx & 31;
    float s = 0.f;
    #pragma unroll
    for (int d = 0; d < 8; ++d) s += tin[r][j + d];
    hs[r][j] = s;
  }
  __syncthreads();
  for (int idx = tid; idx < 32 * 32; idx += 256) {
    int i = idx >> 5, j = idx & 31;
    size_t gofs = (size_t)b * NIMG + (i0 + i) * W + (j0 + j);
    float s = 0.f;
    #pragma unroll
    for (int d = 0; d < 8; ++d) s += hs[i + d][j];
    R[gofs] = E[gofs] * s;
  }
}

extern "C" void kernel_launch(void* const* d_in, const int* in_sizes, int n_in,
                              void* d_out, int out_size, void* d_ws, size_t ws_size,
                              hipStream_t stream) {
  const float* x   = (const float*)d_in[0];
  const float* w1  = (const float*)d_in[1];
  const float* w2  = (const float*)d_in[3];
  const float* g1  = (const float*)d_in[5];
  const float* be1 = (const float*)d_in[6];
  const float* g2  = (const float*)d_in[7];
  const float* be2 = (const float*)d_in[8];

  float* out_c = (float*)d_out;          // C_out: NPIX floats
  float* out_r = out_c + NPIX;           // R: NM floats

  // workspace: p_t 43.9 MB + Epart 11.5 + E 1.6 + S/y2 0.8 + small ≈ 58 MB
  unsigned short* p_t = (unsigned short*)d_ws;          // [7][NPIX][8] bf16
  float* fbase = (float*)(p_t + (size_t)7 * NPIX * 8);
  size_t off = 0;
  float* Epart  = fbase + off; off += (size_t)7 * NM;
  float* E      = fbase + off; off += NM;
  float* Sarr   = fbase + off; off += NPIX;
  float* y2     = fbase + off; off += NPIX;
  float* ypart  = fbase + off; off += (size_t)NGRID * 112;
  float* y2part = fbase + off; off += (size_t)NGRID * 8;
  float* ac     = fbase + off; off += 112;
  float* a2c2   = fbase + off; off += 2;

  pool32_kernel<<<100 * B * 7, 256, 0, stream>>>(x, Epart, p_t);

  dim3 sg(10, 10, B);
  se_pool_kernel<<<sg, 256, 0, stream>>>(Epart, E, Sarr);

  y1_stats_kernel<<<NGRID, 256, 0, stream>>>(p_t, w1, ypart);
  ypart_bn1_kernel<<<1, 128, 0, stream>>>(ypart, g1, be1, ac);
  y2_kernel<<<NGRID, 256, 0, stream>>>(p_t, w1, ac, w2, y2, y2part);
  bn2_final_kernel<<<1, 256, 0, stream>>>(y2part, g2, be2, a2c2);

  dim3 rg(10, 10, B);
  r_pool_kernel<<<rg, 256, 0, stream>>>(y2, Sarr, a2c2, E, out_c, out_r);
}